// Round 1
// baseline (93.456 us; speedup 1.0000x reference)
//
#include <hip/hip_runtime.h>

// Problem constants (from reference setup_inputs)
#define BB 8
#define CC 19
#define HH 512
#define WW 512
#define HW (HH * WW)            // 262144
#define NVOX (BB * HW)          // 2097152
#define NQUAD (NVOX / 4)        // 524288
#define BLOCK 256

// ws layout: [0..CC) int counts | [CC..2*CC) float ce-sums
__global__ void ce_init(int* __restrict__ counts, float* __restrict__ sums) {
    int i = threadIdx.x;
    if (i < CC) { counts[i] = 0; sums[i] = 0.0f; }
}

__global__ __launch_bounds__(BLOCK) void ce_pass1(
        const float* __restrict__ predict,
        const float* __restrict__ target,
        int* __restrict__ g_counts,
        float* __restrict__ g_sums) {
    __shared__ int   s_cnt[CC];
    __shared__ float s_sum[CC];
    const int tid = threadIdx.x;
    if (tid < CC) { s_cnt[tid] = 0; s_sum[tid] = 0.0f; }
    __syncthreads();

    // One quad (4 consecutive voxels) per thread; grid covers NQUAD exactly.
    const int q = blockIdx.x * BLOCK + tid;
    const long base = (long)q * 4;                 // voxel index
    const int  b    = (int)(base >> 18);           // / HW (HW = 2^18)
    const int  hw   = (int)(base & (HW - 1));
    const long off  = (long)b * CC * HW + hw;

    // Per-voxel online state (statically indexed only).
    float tmax[4], ptg[4], m[4], s[4];
    int   targ[4];
    #pragma unroll
    for (int j = 0; j < 4; ++j) {
        tmax[j] = -1e30f; ptg[j] = 0.0f; m[j] = -1e30f; s[j] = 0.0f; targ[j] = 0;
    }

    #pragma unroll
    for (int c = 0; c < CC; ++c) {
        const float4 tv = *reinterpret_cast<const float4*>(target  + off + (long)c * HW);
        const float4 pv = *reinterpret_cast<const float4*>(predict + off + (long)c * HW);
        const float tarr[4] = {tv.x, tv.y, tv.z, tv.w};
        const float parr[4] = {pv.x, pv.y, pv.z, pv.w};
        #pragma unroll
        for (int j = 0; j < 4; ++j) {
            const float t = tarr[j];
            const float p = parr[j];
            // argmax(target) with first-occurrence tie-break (strict >)
            if (t > tmax[j]) { tmax[j] = t; ptg[j] = p; targ[j] = c; }
            // online logsumexp over predict
            const float mn = fmaxf(m[j], p);
            s[j] = s[j] * __expf(m[j] - mn) + __expf(p - mn);
            m[j] = mn;
        }
    }

    #pragma unroll
    for (int j = 0; j < 4; ++j) {
        const float ce = __logf(s[j]) + m[j] - ptg[j];   // = logsumexp - p[argmax]
        atomicAdd(&s_cnt[targ[j]], 1);
        atomicAdd(&s_sum[targ[j]], ce);
    }
    __syncthreads();
    if (tid < CC) {
        atomicAdd(&g_counts[tid], s_cnt[tid]);
        atomicAdd(&g_sums[tid],  s_sum[tid]);
    }
}

__global__ void ce_finalize(const int* __restrict__ counts,
                            const float* __restrict__ sums,
                            float* __restrict__ out) {
    if (threadIdx.x == 0 && blockIdx.x == 0) {
        double tot = 0.0;
        for (int c = 0; c < CC; ++c) {
            const int n = counts[c];
            float w = 1.0f;
            if (n > 0) w = logf((float)NVOX / (float)n);
            tot += (double)w * (double)sums[c];
        }
        out[0] = (float)(tot / (double)NVOX);
    }
}

extern "C" void kernel_launch(void* const* d_in, const int* in_sizes, int n_in,
                              void* d_out, int out_size, void* d_ws, size_t ws_size,
                              hipStream_t stream) {
    const float* predict = (const float*)d_in[0];
    const float* target  = (const float*)d_in[1];
    float* out = (float*)d_out;

    int*   counts = (int*)d_ws;
    float* sums   = (float*)d_ws + CC;

    ce_init<<<1, 64, 0, stream>>>(counts, sums);
    ce_pass1<<<NQUAD / BLOCK, BLOCK, 0, stream>>>(predict, target, counts, sums);
    ce_finalize<<<1, 64, 0, stream>>>(counts, sums, out);
}

// Round 2
// 89.967 us; speedup vs baseline: 1.0388x; 1.0388x over previous
//
#include <hip/hip_runtime.h>

// Problem constants (from reference setup_inputs)
#define BB 8
#define CC 19
#define HH 512
#define WW 512
#define HW (HH * WW)            // 262144 = 2^18
#define NVOX (BB * HW)          // 2097152
#define NQUAD (NVOX / 4)        // 524288
#define BLOCK 256
#define NWAVE (BLOCK / 64)

// ws layout: [0..CC) int counts | [CC..2*CC) float ce-sums
__global__ void ce_init(int* __restrict__ counts, float* __restrict__ sums) {
    int i = threadIdx.x;
    if (i < CC) { counts[i] = 0; sums[i] = 0.0f; }
}

__global__ __launch_bounds__(BLOCK, 2) void ce_pass1(
        const float* __restrict__ predict,
        const float* __restrict__ target,
        int* __restrict__ g_counts,
        float* __restrict__ g_sums) {
    __shared__ int   s_cnt[NWAVE][CC];
    __shared__ float s_sum[NWAVE][CC];
    const int tid = threadIdx.x;
    const int wv  = tid >> 6;
    const int ln  = tid & 63;
    if (ln < CC) { s_cnt[wv][ln] = 0; s_sum[wv][ln] = 0.0f; }
    __syncthreads();

    // One quad (4 consecutive voxels) per thread; grid covers NQUAD exactly.
    const int q = blockIdx.x * BLOCK + tid;
    const long base = (long)q * 4;                 // voxel index
    const int  b    = (int)(base >> 18);           // / HW
    const int  hw   = (int)(base & (HW - 1));
    const float* tp = target  + (long)b * CC * HW + hw;
    const float* pp = predict + (long)b * CC * HW + hw;

    // ---- Stage ALL loads up front: 38 independent dwordx4 in flight ----
    float4 t[CC], p[CC];
    #pragma unroll
    for (int c = 0; c < CC; ++c)
        t[c] = *reinterpret_cast<const float4*>(tp + (long)c * HW);
    #pragma unroll
    for (int c = 0; c < CC; ++c)
        p[c] = *reinterpret_cast<const float4*>(pp + (long)c * HW);

    // ---- argmax over target (first-occurrence tie-break via strict >) ----
    float tmax[4] = {-1e30f, -1e30f, -1e30f, -1e30f};
    int   targ[4] = {0, 0, 0, 0};
    #pragma unroll
    for (int c = 0; c < CC; ++c) {
        if (t[c].x > tmax[0]) { tmax[0] = t[c].x; targ[0] = c; }
        if (t[c].y > tmax[1]) { tmax[1] = t[c].y; targ[1] = c; }
        if (t[c].z > tmax[2]) { tmax[2] = t[c].z; targ[2] = c; }
        if (t[c].w > tmax[3]) { tmax[3] = t[c].w; targ[3] = c; }
    }

    // ---- max over predict ----
    float m[4] = {-1e30f, -1e30f, -1e30f, -1e30f};
    #pragma unroll
    for (int c = 0; c < CC; ++c) {
        m[0] = fmaxf(m[0], p[c].x);
        m[1] = fmaxf(m[1], p[c].y);
        m[2] = fmaxf(m[2], p[c].z);
        m[3] = fmaxf(m[3], p[c].w);
    }

    // ---- sum of exp + select p[targ] ----
    float s[4]   = {0.0f, 0.0f, 0.0f, 0.0f};
    float ptg[4] = {0.0f, 0.0f, 0.0f, 0.0f};
    #pragma unroll
    for (int c = 0; c < CC; ++c) {
        s[0] += __expf(p[c].x - m[0]);  if (c == targ[0]) ptg[0] = p[c].x;
        s[1] += __expf(p[c].y - m[1]);  if (c == targ[1]) ptg[1] = p[c].y;
        s[2] += __expf(p[c].z - m[2]);  if (c == targ[2]) ptg[2] = p[c].z;
        s[3] += __expf(p[c].w - m[3]);  if (c == targ[3]) ptg[3] = p[c].w;
    }

    #pragma unroll
    for (int j = 0; j < 4; ++j) {
        const float ce = __logf(s[j]) + m[j] - ptg[j];   // logsumexp - p[argmax]
        atomicAdd(&s_cnt[wv][targ[j]], 1);
        atomicAdd(&s_sum[wv][targ[j]], ce);
    }
    __syncthreads();
    if (tid < CC) {
        int cs = 0; float ss = 0.0f;
        #pragma unroll
        for (int w = 0; w < NWAVE; ++w) { cs += s_cnt[w][tid]; ss += s_sum[w][tid]; }
        atomicAdd(&g_counts[tid], cs);
        atomicAdd(&g_sums[tid],  ss);
    }
}

__global__ void ce_finalize(const int* __restrict__ counts,
                            const float* __restrict__ sums,
                            float* __restrict__ out) {
    if (threadIdx.x == 0 && blockIdx.x == 0) {
        double tot = 0.0;
        for (int c = 0; c < CC; ++c) {
            const int n = counts[c];
            float w = 1.0f;
            if (n > 0) w = logf((float)NVOX / (float)n);
            tot += (double)w * (double)sums[c];
        }
        out[0] = (float)(tot / (double)NVOX);
    }
}

extern "C" void kernel_launch(void* const* d_in, const int* in_sizes, int n_in,
                              void* d_out, int out_size, void* d_ws, size_t ws_size,
                              hipStream_t stream) {
    const float* predict = (const float*)d_in[0];
    const float* target  = (const float*)d_in[1];
    float* out = (float*)d_out;

    int*   counts = (int*)d_ws;
    float* sums   = (float*)d_ws + CC;

    ce_init<<<1, 64, 0, stream>>>(counts, sums);
    ce_pass1<<<NQUAD / BLOCK, BLOCK, 0, stream>>>(predict, target, counts, sums);
    ce_finalize<<<1, 64, 0, stream>>>(counts, sums, out);
}